// Round 2
// 252.854 us; speedup vs baseline: 1.0046x; 1.0046x over previous
//
#include <hip/hip_runtime.h>
#include <math.h>

typedef float fvec4 __attribute__((ext_vector_type(4)));  // native vector for nontemporal builtin

// Stage 1: spatial mean over H*W=4096 contiguous floats per (b,c,t) row.
// One WAVE (64 lanes) per row: no LDS, no __syncthreads. Each lane loads
// 16 float4s (coalesced: lane i reads float4 index lane + 64*k), giving
// 256 B of outstanding loads per lane. 512-thread blocks = 8 waves = 8
// rows/block -> 1536 blocks for 12288 rows.
// NOTE (R4 post-mortem): do NOT fuse stage 2 into this kernel's tail —
// carrying the PCA register state + per-block device fences cost +78 µs.
// NOTE (R5 theory): x (201 MB) fits in the 256 MB Infinity Cache; this
// kernel is LLC-read-bound (~10 µs), not HBM-bound. Leave structure alone.
__global__ __launch_bounds__(512) void mean_kernel(const float* __restrict__ x,
                                                   float* __restrict__ m) {
    const int wave = threadIdx.x >> 6;             // 0..7
    const int lane = threadIdx.x & 63;
    const int row  = blockIdx.x * 8 + wave;        // 0..12287
    const fvec4* p = (const fvec4*)(x + (size_t)row * 4096);

    // 4096 floats = 1024 float4 per row / 64 lanes = 16 float4 per lane.
    fvec4 v[16];
#pragma unroll
    for (int k = 0; k < 16; ++k)
        v[k] = __builtin_nontemporal_load(&p[lane + 64 * k]);

    float s = 0.f;
#pragma unroll
    for (int k = 0; k < 16; ++k)
        s += (v[k].x + v[k].y) + (v[k].z + v[k].w);

    // wave-level reduce (width 64)
    for (int off = 32; off; off >>= 1) s += __shfl_down(s, off, 64);

    if (lane == 0) m[row] = s * (1.0f / 4096.0f);
}

// Stage 2: per-batch PCA on X[3,512]. One block per batch, 512 threads
// (thread t owns column t). Gram reduce -> 3x3 symmetric eigensolve.
// R5 change: the eigensolve runs REDUNDANTLY on all 512 threads in fp32
// (hardware v_sqrt_f32 / v_cos_f32, short acosf polynomial) instead of
// serially on thread 0 in fp64 (software acos/cos chains ~2-3k cycles
// while 4095 threads idle). This also deletes the second __syncthreads
// and the coef[] LDS broadcast. All lanes compute bit-identical values
// in lockstep, so no broadcast is needed.
// Sign safety: if fp32 picks a different cross-product row than fp64
// (near-tie in norms), v flips to -v but the svd_flip sign s flips with
// it -> output invariant.
__global__ __launch_bounds__(512) void pca_kernel(const float* __restrict__ m,
                                                  float* __restrict__ out) {
    const int b = blockIdx.x;
    const int t = threadIdx.x;                      // 0..511
    const float* X = m + b * 3 * 512;

    const float x0 = X[t], x1 = X[512 + t], x2 = X[1024 + t];
    const float mu = (x0 + x1 + x2) * (1.0f / 3.0f);
    const float c0 = x0 - mu, c1 = x1 - mu, c2 = x2 - mu;

    float g[6] = { c0 * c0, c0 * c1, c0 * c2, c1 * c1, c1 * c2, c2 * c2 };

    __shared__ float red[8][6];
#pragma unroll
    for (int j = 0; j < 6; ++j) {
        float v = g[j];
        for (int off = 32; off; off >>= 1) v += __shfl_down(v, off, 64);
        g[j] = v;
    }
    const int wave = t >> 6, lane = t & 63;
    if (lane == 0) {
#pragma unroll
        for (int j = 0; j < 6; ++j) red[wave][j] = g[j];
    }
    __syncthreads();

    // Final 8-way reduce: every thread reads the same 48 LDS floats
    // (same-address broadcast, conflict-free) and solves redundantly.
    float G[6];
#pragma unroll
    for (int j = 0; j < 6; ++j) {
        float a = 0.f;
#pragma unroll
        for (int w = 0; w < 8; ++w) a += red[w][j];
        G[j] = a;
    }
    const float a00 = G[0], a01 = G[1], a02 = G[2];
    const float a11 = G[3], a12 = G[4], a22 = G[5];

    // Analytic eigenvalues of symmetric 3x3 (trig method), fp32.
    const float q = (a00 + a11 + a22) * (1.0f / 3.0f);
    const float b00 = a00 - q, b11 = a11 - q, b22 = a22 - q;
    const float p2 = b00 * b00 + b11 * b11 + b22 * b22
                   + 2.0f * (a01 * a01 + a02 * a02 + a12 * a12);
    const float p = sqrtf(p2 * (1.0f / 6.0f));
    float l1;  // middle eigenvalue (second singular value squared)
    if (p < 1e-30f) {
        l1 = q;
    } else {
        const float pinv = 1.0f / p;
        const float d00 = b00 * pinv, d11 = b11 * pinv, d22 = b22 * pinv;
        const float d01 = a01 * pinv, d02 = a02 * pinv, d12 = a12 * pinv;
        float r = 0.5f * (d00 * (d11 * d22 - d12 * d12)
                        - d01 * (d01 * d22 - d12 * d02)
                        + d02 * (d01 * d12 - d11 * d02));
        r = fminf(1.0f, fmaxf(-1.0f, r));
        const float phi = acosf(r) * (1.0f / 3.0f);
        const float l_max = q + 2.0f * p * cosf(phi);
        const float l_min = q + 2.0f * p * cosf(phi + 2.0943951023931953f);  // +2pi/3
        l1 = 3.0f * q - l_max - l_min;
    }

    // Eigenvector for l1 via cross products of rows of (A - l1*I).
    const float r0x = a00 - l1, r0y = a01,      r0z = a02;
    const float r1x = a01,      r1y = a11 - l1, r1z = a12;
    const float r2x = a02,      r2y = a12,      r2z = a22 - l1;

    float vax = r0y * r1z - r0z * r1y;
    float vay = r0z * r1x - r0x * r1z;
    float vaz = r0x * r1y - r0y * r1x;
    float vbx = r0y * r2z - r0z * r2y;
    float vby = r0z * r2x - r0x * r2z;
    float vbz = r0x * r2y - r0y * r2x;
    float vcx = r1y * r2z - r1z * r2y;
    float vcy = r1z * r2x - r1x * r2z;
    float vcz = r1x * r2y - r1y * r2x;

    const float na = vax * vax + vay * vay + vaz * vaz;
    const float nb = vbx * vbx + vby * vby + vbz * vbz;
    const float nc = vcx * vcx + vcy * vcy + vcz * vcz;

    float vx = vax, vy = vay, vz = vaz, n = na;
    if (nb > n) { vx = vbx; vy = vby; vz = vbz; n = nb; }
    if (nc > n) { vx = vcx; vy = vcy; vz = vcz; n = nc; }
    const float ninv = (n > 0.0f) ? (1.0f / sqrtf(n)) : 0.0f;
    vx *= ninv; vy *= ninv; vz *= ninv;

    // svd_flip sign: sign of the max-|.| component of u1 (first max).
    int idx = 0;
    float best = fabsf(vx);
    if (fabsf(vy) > best) { best = fabsf(vy); idx = 1; }
    if (fabsf(vz) > best) { best = fabsf(vz); idx = 2; }
    const float comp = (idx == 0) ? vx : (idx == 1) ? vy : vz;
    const float s = (comp >= 0.0f) ? 1.0f : -1.0f;

    // out[t] = s * (u1 . Xc[:,t]) * sqrt(l1) / 2
    const float scale = s * 0.5f * sqrtf(fmaxf(l1, 0.0f));
    out[b * 512 + t] = (vx * scale) * c0 + (vy * scale) * c1 + (vz * scale) * c2;
}

extern "C" void kernel_launch(void* const* d_in, const int* in_sizes, int n_in,
                              void* d_out, int out_size, void* d_ws, size_t ws_size,
                              hipStream_t stream) {
    const float* x = (const float*)d_in[0];   // [8, 3, 512, 64, 64] fp32
    float* out = (float*)d_out;               // [8, 512] fp32
    float* m = (float*)d_ws;                  // [8, 3, 512] spatial means (49 KB)

    const int ROWS = 8 * 3 * 512;             // 12288
    mean_kernel<<<ROWS / 8, 512, 0, stream>>>(x, m);
    pca_kernel<<<8, 512, 0, stream>>>(m, out);
}